// Round 18
// baseline (525.215 us; speedup 1.0000x reference)
//
#include <hip/hip_runtime.h>
#include <hip/hip_bf16.h>
#include <math.h>

typedef __attribute__((ext_vector_type(8))) short short8;
typedef __attribute__((ext_vector_type(4))) float f32x4;

constexpr int nB = 64, nT = 512, nE = 768, nH = 128, nG = 512, nC = 18;
constexpr int nBT = nB * nT;

__device__ __forceinline__ float bf2f(unsigned short u) { return __uint_as_float(((unsigned int)u) << 16); }
__device__ __forceinline__ unsigned short f2bf(float f) {
  __hip_bfloat16 h = __float2bfloat16(f);
  return *reinterpret_cast<unsigned short*>(&h);
}
__device__ __forceinline__ float rlane(float v, int lane) {
  return __uint_as_float(__builtin_amdgcn_readlane(__float_as_uint(v), lane));
}
__device__ __forceinline__ float fast_sig(float x) {
  return __builtin_amdgcn_rcpf(1.0f + __builtin_amdgcn_exp2f(-1.44269504f * x));
}
__device__ __forceinline__ float fast_tanh(float x) {
  return 1.0f - 2.0f * __builtin_amdgcn_rcpf(1.0f + __builtin_amdgcn_exp2f(2.88539008f * x));
}
__device__ __forceinline__ float max3h(float a, float b, float c) { return fmaxf(fmaxf(a, b), c); }

// ---------------- f32 -> bf16 convert: x + both Wih in ONE launch ----------------
__global__ __launch_bounds__(256) void cvt_all(const float* __restrict__ x,
                                               const float* __restrict__ wF,
                                               const float* __restrict__ wB,
                                               unsigned short* __restrict__ xo,
                                               unsigned short* __restrict__ wFo,
                                               unsigned short* __restrict__ wBo) {
  const float* in; unsigned short* out; int n8, bid, nblk;
  if (blockIdx.x < 4096)      { in = x;  out = xo;  n8 = nBT * nE / 8; bid = blockIdx.x;        nblk = 4096; }
  else if (blockIdx.x < 4288) { in = wF; out = wFo; n8 = nG * nE / 8;  bid = blockIdx.x - 4096; nblk = 192; }
  else                        { in = wB; out = wBo; n8 = nG * nE / 8;  bid = blockIdx.x - 4288; nblk = 192; }
  int i = bid * 256 + threadIdx.x;
  const int stride = nblk * 256;
  for (; i < n8; i += stride) {
    const float4 a = ((const float4*)in)[(size_t)i * 2];
    const float4 b = ((const float4*)in)[(size_t)i * 2 + 1];
    unsigned short u[8] = {f2bf(a.x), f2bf(a.y), f2bf(a.z), f2bf(a.w),
                           f2bf(b.x), f2bf(b.y), f2bf(b.z), f2bf(b.w)};
    ((float4*)out)[i] = *(float4*)u;
  }
}

// ---------------- projection GEMM: 128x256 tiles (unchanged from R17) ----------------
__global__ __launch_bounds__(512) void proj_kernel(
    const unsigned short* __restrict__ xbf,
    const unsigned short* __restrict__ wfb, const unsigned short* __restrict__ wbb,
    const float* __restrict__ biasF, const float* __restrict__ biasB,
    unsigned short* __restrict__ Pf, unsigned short* __restrict__ Pb)
{
  const int bid = blockIdx.x;
  const int mt = bid & 255, sub = bid >> 8;
  const int dir = sub >> 1, snt = sub & 1;
  const unsigned short* W = dir ? wbb : wfb;
  const float* bias = dir ? biasB : biasF;
  unsigned short* P = dir ? Pb : Pf;
  const int m0 = mt * 128, n0 = snt * 256;

  __shared__ unsigned short As[128 * 40];
  __shared__ unsigned short Bs[256 * 40];
  const int tid = threadIdx.x;
  const int w = tid >> 6, lane = tid & 63, l15 = lane & 15, l4 = lane >> 4;
  const int wr = w >> 2, wc = w & 3;
  const int arow = tid >> 2, aq = tid & 3;
  const int brow = tid >> 1, bh = tid & 1;

  const unsigned short* srcA = xbf + (size_t)(m0 + arow) * nE + aq * 8;
  const unsigned short* srcB = W + (size_t)(n0 + brow) * nE + bh * 16;

  f32x4 acc[4][4];
#pragma unroll
  for (int i = 0; i < 4; ++i)
#pragma unroll
    for (int j = 0; j < 4; ++j) acc[i][j] = (f32x4){0.f, 0.f, 0.f, 0.f};

  for (int k0 = 0; k0 < nE; k0 += 32) {
    const float4 a0 = *(const float4*)(srcA + k0);
    const float4 b0 = *(const float4*)(srcB + k0);
    const float4 b1 = *(const float4*)(srcB + k0 + 8);
    __syncthreads();
    *(float4*)&As[arow * 40 + aq * 8] = a0;
    *(float4*)&Bs[brow * 40 + bh * 16] = b0;
    *(float4*)&Bs[brow * 40 + bh * 16 + 8] = b1;
    __syncthreads();
    short8 af[4], bfr[4];
#pragma unroll
    for (int i = 0; i < 4; ++i) af[i] = *(const short8*)&As[(wr * 64 + i * 16 + l15) * 40 + l4 * 8];
#pragma unroll
    for (int j = 0; j < 4; ++j) bfr[j] = *(const short8*)&Bs[(wc * 64 + j * 16 + l15) * 40 + l4 * 8];
#pragma unroll
    for (int i = 0; i < 4; ++i)
#pragma unroll
      for (int j = 0; j < 4; ++j)
        acc[i][j] = __builtin_amdgcn_mfma_f32_16x16x32_bf16(af[i], bfr[j], acc[i][j], 0, 0, 0);
  }
  float bv[4];
#pragma unroll
  for (int j = 0; j < 4; ++j) bv[j] = bias[n0 + wc * 64 + j * 16 + l15];
#pragma unroll
  for (int i = 0; i < 4; ++i) {
#pragma unroll
    for (int j = 0; j < 4; ++j) {
      const int col = n0 + wc * 64 + j * 16 + l15;
#pragma unroll
      for (int r = 0; r < 4; ++r) {
        const int row = m0 + wr * 64 + i * 16 + l4 * 4 + r;
        P[(size_t)row * nG + col] = f2bf(acc[i][j][r] + bv[j]);
      }
    }
  }
}

// ---------------- MFMA LSTM v4.1: 32 blocks, 4 batches/block, moving-pointer VALU trim --
// Same math/layout as v4 (proven 250 us). Prefetch + h-store now use incremented
// per-lane pointers (no per-step mul/cndmask addressing). Last-2-step prefetch
// overruns are dead loads landing inside ws (preF is preceded by wbb).
__global__ __launch_bounds__(512, 1) void lstm_kernel(
    const unsigned short* __restrict__ Pf, const unsigned short* __restrict__ Pb,
    const float* __restrict__ WhhF, const float* __restrict__ WhhB,
    unsigned short* __restrict__ hf, unsigned short* __restrict__ hb)
{
  const int bid = blockIdx.x;
  const int dir = bid & 1, grp = bid >> 1;
  const int b0 = grp * 4;
  const unsigned short* pre = dir ? Pb : Pf;
  const float* Whh = dir ? WhhB : WhhF;
  unsigned short* hout = dir ? hb : hf;

  const int tid = threadIdx.x, w = tid >> 6, lane = tid & 63;
  const int l15 = lane & 15, l4 = lane >> 4;
  const int batch = l15 & 3, msel = l15 >> 2;
  const int cell = w * 16 + msel * 4 + l4;
  const int swz = batch * 40;

  __shared__ unsigned short h_lds[2 * 4 * 128];

  short8 Af[4][4];
#pragma unroll
  for (int m = 0; m < 4; ++m) {
    const int gp = w * 64 + m * 16 + l15;
    const int gorig = (gp & 3) * 128 + (gp >> 2);
#pragma unroll
    for (int kk = 0; kk < 4; ++kk) {
      const float* wp = Whh + (size_t)gorig * nH + kk * 32 + l4 * 8;
      const float4 v0 = *(const float4*)wp;
      const float4 v1 = *(const float4*)(wp + 4);
      unsigned short u[8] = {f2bf(v0.x), f2bf(v0.y), f2bf(v0.z), f2bf(v0.w),
                             f2bf(v1.x), f2bf(v1.y), f2bf(v1.z), f2bf(v1.w)};
      Af[m][kk] = *(short8*)u;
    }
  }
  for (int i = tid; i < 2 * 4 * 128; i += 512) h_lds[i] = 0;

  float c_state = 0.f;
  const unsigned short* pbase = pre + (size_t)(b0 + batch) * nT * nG + cell;
  const ptrdiff_t pstep = dir ? -(ptrdiff_t)nG : (ptrdiff_t)nG;   // prefetch stride (elems)
  const ptrdiff_t hstep = dir ? -(ptrdiff_t)nH : (ptrdiff_t)nH;   // h-store stride (elems)

  unsigned short pA[4], pB[4];
  {
    const int tt0 = dir ? (nT - 1) : 0;
    const int tt1 = dir ? (nT - 2) : 1;
#pragma unroll
    for (int r = 0; r < 4; ++r) pA[r] = pbase[(size_t)tt0 * nG + r * 128];
#pragma unroll
    for (int r = 0; r < 4; ++r) pB[r] = pbase[(size_t)tt1 * nG + r * 128];
  }
  // moving pointers: prefetch for t+2, h-store for t
  const unsigned short* pnext = pbase + (size_t)(dir ? (nT - 3) : 2) * nG;
  unsigned short* hcur = hout + ((size_t)(b0 + batch) * nT + (dir ? (nT - 1) : 0)) * nH + cell;
  __syncthreads();

#define LSTM_STEP(RB, BUFC)                                                      \
  {                                                                              \
    float pg[4];                                                                 \
    _Pragma("unroll")                                                            \
    for (int r = 0; r < 4; ++r) pg[r] = bf2f(BUFC[r]);                           \
    _Pragma("unroll")                                                            \
    for (int r = 0; r < 4; ++r) BUFC[r] = pnext[r * 128];                        \
    pnext += pstep;                                                              \
    short8 bfr[4];                                                               \
    _Pragma("unroll")                                                            \
    for (int kk = 0; kk < 4; ++kk) {                                             \
      const int idx = (RB) * 512 + batch * 128 + ((kk * 32 + l4 * 8) ^ swz);     \
      bfr[kk] = *(const short8*)&h_lds[idx];                                     \
    }                                                                            \
    f32x4 acc[4];                                                                \
    _Pragma("unroll")                                                            \
    for (int m = 0; m < 4; ++m) acc[m] = (f32x4){0.f, 0.f, 0.f, 0.f};            \
    _Pragma("unroll")                                                            \
    for (int kk = 0; kk < 4; ++kk)                                               \
      _Pragma("unroll")                                                          \
      for (int m = 0; m < 4; ++m)                                                \
        acc[m] = __builtin_amdgcn_mfma_f32_16x16x32_bf16(Af[m][kk], bfr[kk], acc[m], 0, 0, 0); \
    const float g0 = msel < 2 ? (msel == 0 ? acc[0][0] : acc[1][0]) : (msel == 2 ? acc[2][0] : acc[3][0]); \
    const float g1 = msel < 2 ? (msel == 0 ? acc[0][1] : acc[1][1]) : (msel == 2 ? acc[2][1] : acc[3][1]); \
    const float g2 = msel < 2 ? (msel == 0 ? acc[0][2] : acc[1][2]) : (msel == 2 ? acc[2][2] : acc[3][2]); \
    const float g3 = msel < 2 ? (msel == 0 ? acc[0][3] : acc[1][3]) : (msel == 2 ? acc[2][3] : acc[3][3]); \
    const float gi = g0 + pg[0], gf = g1 + pg[1], gg = g2 + pg[2], go = g3 + pg[3]; \
    c_state = fast_sig(gf) * c_state + fast_sig(gi) * fast_tanh(gg);             \
    const float hval = fast_sig(go) * fast_tanh(c_state);                        \
    const unsigned short hu = f2bf(hval);                                        \
    h_lds[((RB) ^ 1) * 512 + batch * 128 + (cell ^ swz)] = hu;                   \
    *hcur = hu;                                                                  \
    hcur += hstep;                                                               \
    asm volatile("s_waitcnt lgkmcnt(0)" ::: "memory");                           \
    __builtin_amdgcn_sched_barrier(0);                                           \
    __builtin_amdgcn_s_barrier();                                                \
  }

  for (int t2 = 0; t2 < nT; t2 += 2) {
    LSTM_STEP(0, pA)
    LSTM_STEP(1, pB)
  }
#undef LSTM_STEP
}

// ---------------- emissions: em = [hf|hb] @ Wfc^T + bfc ----------------
__global__ __launch_bounds__(256) void em_kernel(
    const unsigned short* __restrict__ hf, const unsigned short* __restrict__ hb,
    const float* __restrict__ Wfc, const float* __restrict__ bfc,
    float* __restrict__ em)
{
  __shared__ float seq[32][260];
  __shared__ float Wf[18][260];
  const int tid = threadIdx.x;
  const int row0 = blockIdx.x * 32;
  for (int i = tid; i < 32 * 32; i += 256) {
    const int r = i >> 5, seg = i & 31;
    const unsigned short* src = (seg < 16) ? (hf + (size_t)(row0 + r) * nH + seg * 8)
                                           : (hb + (size_t)(row0 + r) * nH + (seg - 16) * 8);
    const float4 v = *(const float4*)src;
    const unsigned short* u = (const unsigned short*)&v;
#pragma unroll
    for (int k = 0; k < 8; ++k) seq[r][seg * 8 + k] = bf2f(u[k]);
  }
  for (int i = tid; i < nC * 256; i += 256) {
    const int cc = i >> 8, k = i & 255;
    Wf[cc][k] = Wfc[cc * 256 + k];
  }
  __syncthreads();
  for (int o = tid; o < 32 * nC; o += 256) {
    const int r = o / nC, cc = o - r * nC;
    float acc = bfc[cc];
    const float4* s4 = (const float4*)&seq[r][0];
    const float4* w4 = (const float4*)&Wf[cc][0];
#pragma unroll
    for (int q = 0; q < 64; ++q) {
      const float4 a = s4[q]; const float4 wv = w4[q];
      acc += a.x * wv.x + a.y * wv.y + a.z * wv.z + a.w * wv.w;
    }
    em[(size_t)(row0 + r) * nC + cc] = acc;
  }
}

// ---------------- CRF + Viterbi v5 (unchanged from R17) ----------------
__global__ __launch_bounds__(64) void crfvit_kernel(
    const float* __restrict__ em, const int* __restrict__ labels,
    const int* __restrict__ mask, const float* __restrict__ start,
    const float* __restrict__ endt, const float* __restrict__ trans,
    float* __restrict__ loss_out, float* __restrict__ out_path)
{
  constexpr float K2 = 1.44269504088896f;
  constexpr float LN2 = 0.69314718055995f;
  const int b = blockIdx.x >> 1, role = blockIdx.x & 1;
  const int l = threadIdx.x;
  __shared__ float tr[nC * nC];
  __shared__ unsigned char bp[(nT - 1) * nC];
  __shared__ unsigned char path[nT];
  for (int i = l; i < nC * nC; i += 64) tr[i] = trans[i];
  __syncthreads();
  const float* eb = em + (size_t)b * nT * nC;
  const int lc = l < nC ? l : nC - 1;

#define MAX18T(c) fmaxf(max3h(max3h(c[0], c[1], c[2]), max3h(c[3], c[4], c[5]), max3h(c[6], c[7], c[8])),     \
                        max3h(max3h(c[9], c[10], c[11]), max3h(c[12], c[13], c[14]), max3h(c[15], c[16], c[17])))

  if (role == 0) {
    const int* tg = labels + (size_t)b * nT;
    const int* mk = mask + (size_t)b * nT;

    float np = 0.f; int cnt = 0;
    for (int t = l; t < nT; t += 64) {
      const int tag = tg[t];
      const float e = eb[(size_t)t * nC + tag];
      if (t == 0) np += start[tag] + e;
      else np += (float)mk[t] * (e + tr[tg[t - 1] * nC + tag]);
      cnt += mk[t];
    }
#pragma unroll
    for (int off = 32; off; off >>= 1) { np += __shfl_xor(np, off); cnt += __shfl_xor(cnt, off); }
    const float num = np + endt[tg[cnt - 1]];

    float M2[nC];
#pragma unroll
    for (int i = 0; i < nC; ++i) M2[i] = __builtin_amdgcn_exp2f(tr[i * nC + lc] * K2);

    float alpha2 = (start[lc] + eb[lc]) * K2;
    float ec[8], en[8];
#pragma unroll
    for (int j = 0; j < 8; ++j) ec[j] = eb[j * nC + lc] * K2;
#pragma unroll
    for (int j = 0; j < 8; ++j) en[j] = eb[(8 + j) * nC + lc] * K2;
    unsigned long long mb = __ballot(mk[l] != 0);

#define CRF_STEP(T, E) {                                                          \
      const float A2 = rlane(alpha2, 0);                                          \
      const float vv = __builtin_amdgcn_exp2f(alpha2 - A2);                       \
      float s0 = 0.f, s1 = 0.f, s2 = 0.f;                                         \
      _Pragma("unroll")                                                           \
      for (int i = 0; i < nC; i += 3) {                                           \
        s0 = fmaf(rlane(vv, i), M2[i], s0);                                       \
        s1 = fmaf(rlane(vv, i + 1), M2[i + 1], s1);                               \
        s2 = fmaf(rlane(vv, i + 2), M2[i + 2], s2);                               \
      }                                                                           \
      const float anew = A2 + __builtin_amdgcn_logf((s0 + s1) + s2) + (E);        \
      alpha2 = ((mb >> ((T) & 63)) & 1) ? anew : alpha2;                          \
    }

#pragma unroll
    for (int j = 1; j < 8; ++j) CRF_STEP(j, ec[j])
    for (int c = 1; c < 64; ++c) {
#pragma unroll
      for (int j = 0; j < 8; ++j) ec[j] = en[j];
      const int tn = (c < 63) ? (c + 1) * 8 : 504;
#pragma unroll
      for (int j = 0; j < 8; ++j) en[j] = eb[(size_t)(tn + j) * nC + lc] * K2;
      if ((c & 7) == 0) mb = __ballot(mk[c * 8 + l] != 0);
#pragma unroll
      for (int j = 0; j < 8; ++j) CRF_STEP(c * 8 + j, ec[j])
    }
#undef CRF_STEP
    const float v = (l < nC) ? (alpha2 + endt[l] * K2) : -3.0e38f;
    float m = v;
#pragma unroll
    for (int off = 32; off; off >>= 1) m = fmaxf(m, __shfl_xor(m, off));
    float s = (l < nC) ? __builtin_amdgcn_exp2f(v - m) : 0.f;
#pragma unroll
    for (int off = 32; off; off >>= 1) s += __shfl_xor(s, off);
    if (l == 0) {
      const float llh_b = num - (m + __builtin_amdgcn_logf(s)) * LN2;
      atomicAdd(loss_out, -llh_b / (float)nB);
    }
  } else {
    float trc[nC];
#pragma unroll
    for (int i = 0; i < nC; ++i) trc[i] = tr[i * nC + lc];

    float score_r = start[lc] + eb[lc];
    float ec[8], en[8];
#pragma unroll
    for (int j = 0; j < 8; ++j) ec[j] = eb[j * nC + lc];
#pragma unroll
    for (int j = 0; j < 8; ++j) en[j] = eb[(8 + j) * nC + lc];

#define VIT_STEP(T, E) {                                                          \
      float cand[nC];                                                             \
      _Pragma("unroll")                                                           \
      for (int i = 0; i < nC; ++i) cand[i] = rlane(score_r, i) + trc[i];          \
      const float m = MAX18T(cand);                                               \
      int sel[nC];                                                                \
      _Pragma("unroll")                                                           \
      for (int i = 0; i < nC; ++i) sel[i] = (cand[i] == m) ? i : 63;              \
      int arg = sel[0];                                                           \
      _Pragma("unroll")                                                           \
      for (int i = 1; i < nC; ++i) arg = min(arg, sel[i]);                        \
      score_r = m + (E);                                                          \
      if (l < nC) bp[((T) - 1) * nC + l] = (unsigned char)arg;                    \
    }

#pragma unroll
    for (int j = 1; j < 8; ++j) VIT_STEP(j, ec[j])
    for (int c = 1; c < 64; ++c) {
#pragma unroll
      for (int j = 0; j < 8; ++j) ec[j] = en[j];
      const int tn = (c < 63) ? (c + 1) * 8 : 504;
#pragma unroll
      for (int j = 0; j < 8; ++j) en[j] = eb[(size_t)(tn + j) * nC + lc];
#pragma unroll
      for (int j = 0; j < 8; ++j) VIT_STEP(c * 8 + j, ec[j])
    }
#undef VIT_STEP
    if (l == 0) {
      float mm = -3.0e38f; int last = 0;
      for (int i = 0; i < nC; ++i) {
        const float v = rlane(score_r, i) + endt[i];
        if (v > mm) { mm = v; last = i; }
      }
      path[nT - 1] = (unsigned char)last;
      int cur = last;
      for (int t = nT - 2; t >= 0; --t) { cur = bp[t * nC + cur]; path[t] = (unsigned char)cur; }
    }
    asm volatile("s_waitcnt lgkmcnt(0)" ::: "memory");
    __builtin_amdgcn_wave_barrier();
    for (int t = l; t < nT; t += 64) out_path[(size_t)b * nT + t] = (float)(path[t] + 1);
  }
#undef MAX18T
}

extern "C" void kernel_launch(void* const* d_in, const int* in_sizes, int n_in,
                              void* d_out, int out_size, void* d_ws, size_t ws_size,
                              hipStream_t stream)
{
  const float* x      = (const float*)d_in[0];
  const int*   amask  = (const int*)d_in[1];
  const int*   labels = (const int*)d_in[2];
  const float* Wih_f  = (const float*)d_in[3];
  const float* Whh_f  = (const float*)d_in[4];
  const float* b_f    = (const float*)d_in[5];
  const float* Wih_b  = (const float*)d_in[6];
  const float* Whh_b  = (const float*)d_in[7];
  const float* b_b    = (const float*)d_in[8];
  const float* Wfc    = (const float*)d_in[9];
  const float* bfc    = (const float*)d_in[10];
  const float* start  = (const float*)d_in[11];
  const float* endt   = (const float*)d_in[12];
  const float* trans  = (const float*)d_in[13];

  float* out = (float*)d_out;
  // ws layout: xbf/wfb/wbb FIRST so lstm's prefetch underrun (pbase - nG) stays in ws.
  unsigned short* xbf  = (unsigned short*)d_ws;                    // 25.2M bf16
  unsigned short* wfb  = xbf + (size_t)nBT * nE;                   // 393K bf16
  unsigned short* wbb  = wfb + (size_t)nG * nE;                    // 393K bf16
  unsigned short* preF = wbb + (size_t)nG * nE;                    // 16.7M bf16
  unsigned short* preB = preF + (size_t)nBT * nG;                  // 16.7M bf16
  unsigned short* hf   = preB + (size_t)nBT * nG;                  // 4.2M bf16
  unsigned short* hb   = hf + (size_t)nBT * nH;                    // 4.2M bf16
  float* em = (float*)(hb + (size_t)nBT * nH);                     // 590K f32

  hipMemsetAsync(out + nBT, 0, sizeof(float), stream);
  cvt_all<<<4480, 256, 0, stream>>>(x, Wih_f, Wih_b, xbf, wfb, wbb);
  proj_kernel<<<1024, 512, 0, stream>>>(xbf, wfb, wbb, b_f, b_b, preF, preB);
  lstm_kernel<<<32, 512, 0, stream>>>(preF, preB, Whh_f, Whh_b, hf, hb);
  em_kernel<<<1024, 256, 0, stream>>>(hf, hb, Wfc, bfc, em);
  crfvit_kernel<<<128, 64, 0, stream>>>(em, labels, amask, start, endt, trans, out + nBT, out);
}

// Round 19
// 517.778 us; speedup vs baseline: 1.0144x; 1.0144x over previous
//
#include <hip/hip_runtime.h>
#include <hip/hip_bf16.h>
#include <math.h>

typedef __attribute__((ext_vector_type(8))) short short8;
typedef __attribute__((ext_vector_type(4))) float f32x4;

constexpr int nB = 64, nT = 512, nE = 768, nH = 128, nG = 512, nC = 18;
constexpr int nBT = nB * nT;

__device__ __forceinline__ float bf2f(unsigned short u) { return __uint_as_float(((unsigned int)u) << 16); }
__device__ __forceinline__ unsigned short f2bf(float f) {
  __hip_bfloat16 h = __float2bfloat16(f);
  return *reinterpret_cast<unsigned short*>(&h);
}
__device__ __forceinline__ float rlane(float v, int lane) {
  return __uint_as_float(__builtin_amdgcn_readlane(__float_as_uint(v), lane));
}
__device__ __forceinline__ float fast_sig(float x) {
  return __builtin_amdgcn_rcpf(1.0f + __builtin_amdgcn_exp2f(-1.44269504f * x));
}
__device__ __forceinline__ float fast_tanh(float x) {
  return 1.0f - 2.0f * __builtin_amdgcn_rcpf(1.0f + __builtin_amdgcn_exp2f(2.88539008f * x));
}
__device__ __forceinline__ float max3h(float a, float b, float c) { return fmaxf(fmaxf(a, b), c); }

// ---------------- f32 -> bf16 convert: x + both Wih in ONE launch ----------------
__global__ __launch_bounds__(256) void cvt_all(const float* __restrict__ x,
                                               const float* __restrict__ wF,
                                               const float* __restrict__ wB,
                                               unsigned short* __restrict__ xo,
                                               unsigned short* __restrict__ wFo,
                                               unsigned short* __restrict__ wBo) {
  const float* in; unsigned short* out; int n8, bid, nblk;
  if (blockIdx.x < 4096)      { in = x;  out = xo;  n8 = nBT * nE / 8; bid = blockIdx.x;        nblk = 4096; }
  else if (blockIdx.x < 4288) { in = wF; out = wFo; n8 = nG * nE / 8;  bid = blockIdx.x - 4096; nblk = 192; }
  else                        { in = wB; out = wBo; n8 = nG * nE / 8;  bid = blockIdx.x - 4288; nblk = 192; }
  int i = bid * 256 + threadIdx.x;
  const int stride = nblk * 256;
  for (; i < n8; i += stride) {
    const float4 a = ((const float4*)in)[(size_t)i * 2];
    const float4 b = ((const float4*)in)[(size_t)i * 2 + 1];
    unsigned short u[8] = {f2bf(a.x), f2bf(a.y), f2bf(a.z), f2bf(a.w),
                           f2bf(b.x), f2bf(b.y), f2bf(b.z), f2bf(b.w)};
    ((float4*)out)[i] = *(float4*)u;
  }
}

// ---------------- projection GEMM v3: 128x256 tiles, global_load_lds + LDS dbuf --------
// m97 pattern: one barrier per K-iter; tile k+1's loads issued after the barrier so they
// stay in flight through the MFMA phase. Linear un-padded LDS (required by
// global_load_lds): As[2][128][32], Bs[2][256][32] shorts.
__global__ __launch_bounds__(512) void proj_kernel(
    const unsigned short* __restrict__ xbf,
    const unsigned short* __restrict__ wfb, const unsigned short* __restrict__ wbb,
    const float* __restrict__ biasF, const float* __restrict__ biasB,
    unsigned short* __restrict__ Pf, unsigned short* __restrict__ Pb)
{
  const int bid = blockIdx.x;
  const int mt = bid & 255, sub = bid >> 8;
  const int dir = sub >> 1, snt = sub & 1;
  const unsigned short* W = dir ? wbb : wfb;
  const float* bias = dir ? biasB : biasF;
  unsigned short* P = dir ? Pb : Pf;
  const int m0 = mt * 128, n0 = snt * 256;

  __shared__ unsigned short As[2][128 * 32];   // 16 KB
  __shared__ unsigned short Bs[2][256 * 32];   // 32 KB
  const int tid = threadIdx.x;
  const int w = tid >> 6, lane = tid & 63, l15 = lane & 15, l4 = lane >> 4;
  const int wr = w >> 2, wc = w & 3;
  const int arow = tid >> 2, ach = tid & 3;    // staging: row = tid>>2, 8-short chunk = tid&3

  const unsigned short* srcA  = xbf + (size_t)(m0 + arow) * nE + ach * 8;
  const unsigned short* srcB0 = W + (size_t)(n0 + arow) * nE + ach * 8;
  const unsigned short* srcB1 = W + (size_t)(n0 + 128 + arow) * nE + ach * 8;

#define STAGE(BF, K0)                                                              \
  {                                                                                \
    __builtin_amdgcn_global_load_lds(srcA + (K0), &As[BF][w * 512], 16, 0, 0);     \
    __builtin_amdgcn_global_load_lds(srcB0 + (K0), &Bs[BF][w * 512], 16, 0, 0);    \
    __builtin_amdgcn_global_load_lds(srcB1 + (K0), &Bs[BF][4096 + w * 512], 16, 0, 0); \
  }

  f32x4 acc[4][4];
#pragma unroll
  for (int i = 0; i < 4; ++i)
#pragma unroll
    for (int j = 0; j < 4; ++j) acc[i][j] = (f32x4){0.f, 0.f, 0.f, 0.f};

  STAGE(0, 0)
  for (int ki = 0; ki < nE / 32; ++ki) {
    const int bf = ki & 1;
    __syncthreads();                       // drains vmcnt: tile ki resident
    if (ki + 1 < nE / 32) STAGE(bf ^ 1, (ki + 1) * 32)
    short8 af[4], bfr[4];
#pragma unroll
    for (int i = 0; i < 4; ++i) af[i] = *(const short8*)&As[bf][(wr * 64 + i * 16 + l15) * 32 + l4 * 8];
#pragma unroll
    for (int j = 0; j < 4; ++j) bfr[j] = *(const short8*)&Bs[bf][(wc * 64 + j * 16 + l15) * 32 + l4 * 8];
#pragma unroll
    for (int i = 0; i < 4; ++i)
#pragma unroll
      for (int j = 0; j < 4; ++j)
        acc[i][j] = __builtin_amdgcn_mfma_f32_16x16x32_bf16(af[i], bfr[j], acc[i][j], 0, 0, 0);
  }
#undef STAGE
  float bv[4];
#pragma unroll
  for (int j = 0; j < 4; ++j) bv[j] = bias[n0 + wc * 64 + j * 16 + l15];
#pragma unroll
  for (int i = 0; i < 4; ++i) {
#pragma unroll
    for (int j = 0; j < 4; ++j) {
      const int col = n0 + wc * 64 + j * 16 + l15;
#pragma unroll
      for (int r = 0; r < 4; ++r) {
        const int row = m0 + wr * 64 + i * 16 + l4 * 4 + r;
        P[(size_t)row * nG + col] = f2bf(acc[i][j][r] + bv[j]);
      }
    }
  }
}

// ---------------- MFMA LSTM v4.1 (250 us floor): 32 blocks, 4 batches/block ------------
__global__ __launch_bounds__(512, 1) void lstm_kernel(
    const unsigned short* __restrict__ Pf, const unsigned short* __restrict__ Pb,
    const float* __restrict__ WhhF, const float* __restrict__ WhhB,
    unsigned short* __restrict__ hf, unsigned short* __restrict__ hb)
{
  const int bid = blockIdx.x;
  const int dir = bid & 1, grp = bid >> 1;
  const int b0 = grp * 4;
  const unsigned short* pre = dir ? Pb : Pf;
  const float* Whh = dir ? WhhB : WhhF;
  unsigned short* hout = dir ? hb : hf;

  const int tid = threadIdx.x, w = tid >> 6, lane = tid & 63;
  const int l15 = lane & 15, l4 = lane >> 4;
  const int batch = l15 & 3, msel = l15 >> 2;
  const int cell = w * 16 + msel * 4 + l4;
  const int swz = batch * 40;

  __shared__ unsigned short h_lds[2 * 4 * 128];

  short8 Af[4][4];
#pragma unroll
  for (int m = 0; m < 4; ++m) {
    const int gp = w * 64 + m * 16 + l15;
    const int gorig = (gp & 3) * 128 + (gp >> 2);
#pragma unroll
    for (int kk = 0; kk < 4; ++kk) {
      const float* wp = Whh + (size_t)gorig * nH + kk * 32 + l4 * 8;
      const float4 v0 = *(const float4*)wp;
      const float4 v1 = *(const float4*)(wp + 4);
      unsigned short u[8] = {f2bf(v0.x), f2bf(v0.y), f2bf(v0.z), f2bf(v0.w),
                             f2bf(v1.x), f2bf(v1.y), f2bf(v1.z), f2bf(v1.w)};
      Af[m][kk] = *(short8*)u;
    }
  }
  for (int i = tid; i < 2 * 4 * 128; i += 512) h_lds[i] = 0;

  float c_state = 0.f;
  const unsigned short* pbase = pre + (size_t)(b0 + batch) * nT * nG + cell;
  const ptrdiff_t pstep = dir ? -(ptrdiff_t)nG : (ptrdiff_t)nG;
  const ptrdiff_t hstep = dir ? -(ptrdiff_t)nH : (ptrdiff_t)nH;

  unsigned short pA[4], pB[4];
  {
    const int tt0 = dir ? (nT - 1) : 0;
    const int tt1 = dir ? (nT - 2) : 1;
#pragma unroll
    for (int r = 0; r < 4; ++r) pA[r] = pbase[(size_t)tt0 * nG + r * 128];
#pragma unroll
    for (int r = 0; r < 4; ++r) pB[r] = pbase[(size_t)tt1 * nG + r * 128];
  }
  const unsigned short* pnext = pbase + (size_t)(dir ? (nT - 3) : 2) * nG;
  unsigned short* hcur = hout + ((size_t)(b0 + batch) * nT + (dir ? (nT - 1) : 0)) * nH + cell;
  __syncthreads();

#define LSTM_STEP(RB, BUFC)                                                      \
  {                                                                              \
    float pg[4];                                                                 \
    _Pragma("unroll")                                                            \
    for (int r = 0; r < 4; ++r) pg[r] = bf2f(BUFC[r]);                           \
    _Pragma("unroll")                                                            \
    for (int r = 0; r < 4; ++r) BUFC[r] = pnext[r * 128];                        \
    pnext += pstep;                                                              \
    short8 bfr[4];                                                               \
    _Pragma("unroll")                                                            \
    for (int kk = 0; kk < 4; ++kk) {                                             \
      const int idx = (RB) * 512 + batch * 128 + ((kk * 32 + l4 * 8) ^ swz);     \
      bfr[kk] = *(const short8*)&h_lds[idx];                                     \
    }                                                                            \
    f32x4 acc[4];                                                                \
    _Pragma("unroll")                                                            \
    for (int m = 0; m < 4; ++m) acc[m] = (f32x4){0.f, 0.f, 0.f, 0.f};            \
    _Pragma("unroll")                                                            \
    for (int kk = 0; kk < 4; ++kk)                                               \
      _Pragma("unroll")                                                          \
      for (int m = 0; m < 4; ++m)                                                \
        acc[m] = __builtin_amdgcn_mfma_f32_16x16x32_bf16(Af[m][kk], bfr[kk], acc[m], 0, 0, 0); \
    const float g0 = msel < 2 ? (msel == 0 ? acc[0][0] : acc[1][0]) : (msel == 2 ? acc[2][0] : acc[3][0]); \
    const float g1 = msel < 2 ? (msel == 0 ? acc[0][1] : acc[1][1]) : (msel == 2 ? acc[2][1] : acc[3][1]); \
    const float g2 = msel < 2 ? (msel == 0 ? acc[0][2] : acc[1][2]) : (msel == 2 ? acc[2][2] : acc[3][2]); \
    const float g3 = msel < 2 ? (msel == 0 ? acc[0][3] : acc[1][3]) : (msel == 2 ? acc[2][3] : acc[3][3]); \
    const float gi = g0 + pg[0], gf = g1 + pg[1], gg = g2 + pg[2], go = g3 + pg[3]; \
    c_state = fast_sig(gf) * c_state + fast_sig(gi) * fast_tanh(gg);             \
    const float hval = fast_sig(go) * fast_tanh(c_state);                        \
    const unsigned short hu = f2bf(hval);                                        \
    h_lds[((RB) ^ 1) * 512 + batch * 128 + (cell ^ swz)] = hu;                   \
    *hcur = hu;                                                                  \
    hcur += hstep;                                                               \
    asm volatile("s_waitcnt lgkmcnt(0)" ::: "memory");                           \
    __builtin_amdgcn_sched_barrier(0);                                           \
    __builtin_amdgcn_s_barrier();                                                \
  }

  for (int t2 = 0; t2 < nT; t2 += 2) {
    LSTM_STEP(0, pA)
    LSTM_STEP(1, pB)
  }
#undef LSTM_STEP
}

// ---------------- emissions: em = [hf|hb] @ Wfc^T + bfc ----------------
__global__ __launch_bounds__(256) void em_kernel(
    const unsigned short* __restrict__ hf, const unsigned short* __restrict__ hb,
    const float* __restrict__ Wfc, const float* __restrict__ bfc,
    float* __restrict__ em)
{
  __shared__ float seq[32][260];
  __shared__ float Wf[18][260];
  const int tid = threadIdx.x;
  const int row0 = blockIdx.x * 32;
  for (int i = tid; i < 32 * 32; i += 256) {
    const int r = i >> 5, seg = i & 31;
    const unsigned short* src = (seg < 16) ? (hf + (size_t)(row0 + r) * nH + seg * 8)
                                           : (hb + (size_t)(row0 + r) * nH + (seg - 16) * 8);
    const float4 v = *(const float4*)src;
    const unsigned short* u = (const unsigned short*)&v;
#pragma unroll
    for (int k = 0; k < 8; ++k) seq[r][seg * 8 + k] = bf2f(u[k]);
  }
  for (int i = tid; i < nC * 256; i += 256) {
    const int cc = i >> 8, k = i & 255;
    Wf[cc][k] = Wfc[cc * 256 + k];
  }
  __syncthreads();
  for (int o = tid; o < 32 * nC; o += 256) {
    const int r = o / nC, cc = o - r * nC;
    float acc = bfc[cc];
    const float4* s4 = (const float4*)&seq[r][0];
    const float4* w4 = (const float4*)&Wf[cc][0];
#pragma unroll
    for (int q = 0; q < 64; ++q) {
      const float4 a = s4[q]; const float4 wv = w4[q];
      acc += a.x * wv.x + a.y * wv.y + a.z * wv.z + a.w * wv.w;
    }
    em[(size_t)(row0 + r) * nC + cc] = acc;
  }
}

// ---------------- CRF + Viterbi v5 (unchanged) ----------------
__global__ __launch_bounds__(64) void crfvit_kernel(
    const float* __restrict__ em, const int* __restrict__ labels,
    const int* __restrict__ mask, const float* __restrict__ start,
    const float* __restrict__ endt, const float* __restrict__ trans,
    float* __restrict__ loss_out, float* __restrict__ out_path)
{
  constexpr float K2 = 1.44269504088896f;
  constexpr float LN2 = 0.69314718055995f;
  const int b = blockIdx.x >> 1, role = blockIdx.x & 1;
  const int l = threadIdx.x;
  __shared__ float tr[nC * nC];
  __shared__ unsigned char bp[(nT - 1) * nC];
  __shared__ unsigned char path[nT];
  for (int i = l; i < nC * nC; i += 64) tr[i] = trans[i];
  __syncthreads();
  const float* eb = em + (size_t)b * nT * nC;
  const int lc = l < nC ? l : nC - 1;

#define MAX18T(c) fmaxf(max3h(max3h(c[0], c[1], c[2]), max3h(c[3], c[4], c[5]), max3h(c[6], c[7], c[8])),     \
                        max3h(max3h(c[9], c[10], c[11]), max3h(c[12], c[13], c[14]), max3h(c[15], c[16], c[17])))

  if (role == 0) {
    const int* tg = labels + (size_t)b * nT;
    const int* mk = mask + (size_t)b * nT;

    float np = 0.f; int cnt = 0;
    for (int t = l; t < nT; t += 64) {
      const int tag = tg[t];
      const float e = eb[(size_t)t * nC + tag];
      if (t == 0) np += start[tag] + e;
      else np += (float)mk[t] * (e + tr[tg[t - 1] * nC + tag]);
      cnt += mk[t];
    }
#pragma unroll
    for (int off = 32; off; off >>= 1) { np += __shfl_xor(np, off); cnt += __shfl_xor(cnt, off); }
    const float num = np + endt[tg[cnt - 1]];

    float M2[nC];
#pragma unroll
    for (int i = 0; i < nC; ++i) M2[i] = __builtin_amdgcn_exp2f(tr[i * nC + lc] * K2);

    float alpha2 = (start[lc] + eb[lc]) * K2;
    float ec[8], en[8];
#pragma unroll
    for (int j = 0; j < 8; ++j) ec[j] = eb[j * nC + lc] * K2;
#pragma unroll
    for (int j = 0; j < 8; ++j) en[j] = eb[(8 + j) * nC + lc] * K2;
    unsigned long long mb = __ballot(mk[l] != 0);

#define CRF_STEP(T, E) {                                                          \
      const float A2 = rlane(alpha2, 0);                                          \
      const float vv = __builtin_amdgcn_exp2f(alpha2 - A2);                       \
      float s0 = 0.f, s1 = 0.f, s2 = 0.f;                                         \
      _Pragma("unroll")                                                           \
      for (int i = 0; i < nC; i += 3) {                                           \
        s0 = fmaf(rlane(vv, i), M2[i], s0);                                       \
        s1 = fmaf(rlane(vv, i + 1), M2[i + 1], s1);                               \
        s2 = fmaf(rlane(vv, i + 2), M2[i + 2], s2);                               \
      }                                                                           \
      const float anew = A2 + __builtin_amdgcn_logf((s0 + s1) + s2) + (E);        \
      alpha2 = ((mb >> ((T) & 63)) & 1) ? anew : alpha2;                          \
    }

#pragma unroll
    for (int j = 1; j < 8; ++j) CRF_STEP(j, ec[j])
    for (int c = 1; c < 64; ++c) {
#pragma unroll
      for (int j = 0; j < 8; ++j) ec[j] = en[j];
      const int tn = (c < 63) ? (c + 1) * 8 : 504;
#pragma unroll
      for (int j = 0; j < 8; ++j) en[j] = eb[(size_t)(tn + j) * nC + lc] * K2;
      if ((c & 7) == 0) mb = __ballot(mk[c * 8 + l] != 0);
#pragma unroll
      for (int j = 0; j < 8; ++j) CRF_STEP(c * 8 + j, ec[j])
    }
#undef CRF_STEP
    const float v = (l < nC) ? (alpha2 + endt[l] * K2) : -3.0e38f;
    float m = v;
#pragma unroll
    for (int off = 32; off; off >>= 1) m = fmaxf(m, __shfl_xor(m, off));
    float s = (l < nC) ? __builtin_amdgcn_exp2f(v - m) : 0.f;
#pragma unroll
    for (int off = 32; off; off >>= 1) s += __shfl_xor(s, off);
    if (l == 0) {
      const float llh_b = num - (m + __builtin_amdgcn_logf(s)) * LN2;
      atomicAdd(loss_out, -llh_b / (float)nB);
    }
  } else {
    float trc[nC];
#pragma unroll
    for (int i = 0; i < nC; ++i) trc[i] = tr[i * nC + lc];

    float score_r = start[lc] + eb[lc];
    float ec[8], en[8];
#pragma unroll
    for (int j = 0; j < 8; ++j) ec[j] = eb[j * nC + lc];
#pragma unroll
    for (int j = 0; j < 8; ++j) en[j] = eb[(8 + j) * nC + lc];

#define VIT_STEP(T, E) {                                                          \
      float cand[nC];                                                             \
      _Pragma("unroll")                                                           \
      for (int i = 0; i < nC; ++i) cand[i] = rlane(score_r, i) + trc[i];          \
      const float m = MAX18T(cand);                                               \
      int sel[nC];                                                                \
      _Pragma("unroll")                                                           \
      for (int i = 0; i < nC; ++i) sel[i] = (cand[i] == m) ? i : 63;              \
      int arg = sel[0];                                                           \
      _Pragma("unroll")                                                           \
      for (int i = 1; i < nC; ++i) arg = min(arg, sel[i]);                        \
      score_r = m + (E);                                                          \
      if (l < nC) bp[((T) - 1) * nC + l] = (unsigned char)arg;                    \
    }

#pragma unroll
    for (int j = 1; j < 8; ++j) VIT_STEP(j, ec[j])
    for (int c = 1; c < 64; ++c) {
#pragma unroll
      for (int j = 0; j < 8; ++j) ec[j] = en[j];
      const int tn = (c < 63) ? (c + 1) * 8 : 504;
#pragma unroll
      for (int j = 0; j < 8; ++j) en[j] = eb[(size_t)(tn + j) * nC + lc];
#pragma unroll
      for (int j = 0; j < 8; ++j) VIT_STEP(c * 8 + j, ec[j])
    }
#undef VIT_STEP
    if (l == 0) {
      float mm = -3.0e38f; int last = 0;
      for (int i = 0; i < nC; ++i) {
        const float v = rlane(score_r, i) + endt[i];
        if (v > mm) { mm = v; last = i; }
      }
      path[nT - 1] = (unsigned char)last;
      int cur = last;
      for (int t = nT - 2; t >= 0; --t) { cur = bp[t * nC + cur]; path[t] = (unsigned char)cur; }
    }
    asm volatile("s_waitcnt lgkmcnt(0)" ::: "memory");
    __builtin_amdgcn_wave_barrier();
    for (int t = l; t < nT; t += 64) out_path[(size_t)b * nT + t] = (float)(path[t] + 1);
  }
#undef MAX18T
}

extern "C" void kernel_launch(void* const* d_in, const int* in_sizes, int n_in,
                              void* d_out, int out_size, void* d_ws, size_t ws_size,
                              hipStream_t stream)
{
  const float* x      = (const float*)d_in[0];
  const int*   amask  = (const int*)d_in[1];
  const int*   labels = (const int*)d_in[2];
  const float* Wih_f  = (const float*)d_in[3];
  const float* Whh_f  = (const float*)d_in[4];
  const float* b_f    = (const float*)d_in[5];
  const float* Wih_b  = (const float*)d_in[6];
  const float* Whh_b  = (const float*)d_in[7];
  const float* b_b    = (const float*)d_in[8];
  const float* Wfc    = (const float*)d_in[9];
  const float* bfc    = (const float*)d_in[10];
  const float* start  = (const float*)d_in[11];
  const float* endt   = (const float*)d_in[12];
  const float* trans  = (const float*)d_in[13];

  float* out = (float*)d_out;
  unsigned short* xbf  = (unsigned short*)d_ws;                    // 25.2M bf16
  unsigned short* wfb  = xbf + (size_t)nBT * nE;                   // 393K bf16
  unsigned short* wbb  = wfb + (size_t)nG * nE;                    // 393K bf16
  unsigned short* preF = wbb + (size_t)nG * nE;                    // 16.7M bf16
  unsigned short* preB = preF + (size_t)nBT * nG;                  // 16.7M bf16
  unsigned short* hf   = preB + (size_t)nBT * nG;                  // 4.2M bf16
  unsigned short* hb   = hf + (size_t)nBT * nH;                    // 4.2M bf16
  float* em = (float*)(hb + (size_t)nBT * nH);                     // 590K f32

  hipMemsetAsync(out + nBT, 0, sizeof(float), stream);
  cvt_all<<<4480, 256, 0, stream>>>(x, Wih_f, Wih_b, xbf, wfb, wbb);
  proj_kernel<<<1024, 512, 0, stream>>>(xbf, wfb, wbb, b_f, b_b, preF, preB);
  lstm_kernel<<<32, 512, 0, stream>>>(preF, preB, Whh_f, Whh_b, hf, hb);
  em_kernel<<<1024, 256, 0, stream>>>(hf, hb, Wfc, bfc, em);
  crfvit_kernel<<<128, 64, 0, stream>>>(em, labels, amask, start, endt, trans, out + nBT, out);
}